// Round 10
// baseline (182.663 us; speedup 1.0000x reference)
//
#include <hip/hip_runtime.h>
#include <hip/hip_bf16.h>

typedef _Float16 f16x8 __attribute__((ext_vector_type(8)));
typedef float f32x4 __attribute__((ext_vector_type(4)));

#define N_ROWS 4096
#define F_DIM 64
#define EMPF 0.1f
#define EMPD 0.1
#define ZEROV 9e-15f
#define WINDOW 2e-4f
#define REG_CAP 256u      // per-block flagged-entry slots; E[count]=15, P(>256)~e^-200
#define N_BLOCKS 4096     // 32*32*4 gram blocks

// =================== R10: COUNTER-VISIBILITY ROUND ==========================
// R2-R9: seven store/structure levers, zero wins; gram stuck ~115us but its
// counters are INVISIBLE (harness 1GB poison-fills at 155-170us own the
// top-5 table). This round: exact R5 pipeline, but gram runs its body TWICE
// in one dispatch (identical outputs; flags on pass 1 only) -> ~230us
// dispatch tops the table -> full PMC for gram next round.
// Readout plan: WRITE~537MB @~5TB/s & low VALU/MFMA -> DRAM-level write cost;
// FETCH >> 34MB -> L2 panel eviction by write stream; Occupancy<15% or
// VALUBusy>30% -> latency/issue bound.
// ============================================================================

// ---------------- Kernel 1: xw = x*w, normalize, split fp32 -> f16 hi/lo ----
__global__ __launch_bounds__(256) void normalize_split_kernel(
    const float* __restrict__ x, const float* __restrict__ w,
    _Float16* __restrict__ hi, _Float16* __restrict__ lo) {
  const int lane = threadIdx.x & 63;
  const int wid = threadIdx.x >> 6;
  const int rg = blockIdx.x * 4 + wid;          // global row 0..16383 (b*4096+n)
  const int n = rg & (N_ROWS - 1);
  const float xv = x[rg * F_DIM + lane];
  const float wv = w[n * F_DIM + lane];
  const float p = xv * wv;
  float s = p * p;
#pragma unroll
  for (int off = 32; off >= 1; off >>= 1) s += __shfl_xor(s, off, 64);
  const float nrm = fmaxf(sqrtf(s), 1e-8f);
  const float xn = p / nrm;
  const _Float16 h = (_Float16)xn;
  const float rem = xn - (float)h;
  hi[rg * F_DIM + lane] = h;
  lo[rg * F_DIM + lane] = (_Float16)rem;
}

// ---------------- Kernel 2: R5 gram, body executed twice --------------------
__global__ __launch_bounds__(256) void gram_kernel(
    const _Float16* __restrict__ hi, const _Float16* __restrict__ lo,
    float* __restrict__ out, unsigned* __restrict__ cnt,
    unsigned* __restrict__ regions) {
  __shared__ unsigned lds_cnt;

  const int lane = threadIdx.x & 63;
  const int wid = threadIdx.x >> 6;
  const int wm = wid >> 1, wn = wid & 1;
  const int b = blockIdx.z;
  const int row0 = blockIdx.x * 128 + wm * 64;
  const int col0 = blockIdx.y * 128 + wn * 64;
  const int rbase = b * N_ROWS;
  const unsigned bid =
      ((unsigned)blockIdx.z * gridDim.y + blockIdx.y) * gridDim.x + blockIdx.x;
  unsigned* __restrict__ region = regions + (size_t)bid * REG_CAP;

  const int lr = lane & 15;         // fragment row
  const int lk = (lane >> 4) * 8;   // fragment k offset
  const int r_in = lane & 15;       // C/D (transposed): row index within frag
  const int cb = (lane >> 4) * 4;   // col base within frag

#pragma unroll 1
  for (int pass = 0; pass < 2; ++pass) {
    if (threadIdx.x == 0) lds_cnt = 0;
    __syncthreads();

    // Row-panel (a-side) fragments.
    f16x8 ah[2][4], al[2][4];
#pragma unroll
    for (int kf = 0; kf < 2; ++kf)
#pragma unroll
      for (int i = 0; i < 4; ++i) {
        const int ra = (rbase + row0 + i * 16 + lr) * F_DIM + kf * 32 + lk;
        ah[kf][i] = *(const f16x8*)(hi + ra);
        al[kf][i] = *(const f16x8*)(lo + ra);
      }

#pragma unroll 1
    for (int j = 0; j < 4; ++j) {
      f16x8 bh[2], bl[2];
#pragma unroll
      for (int kf = 0; kf < 2; ++kf) {
        const int rb = (rbase + col0 + j * 16 + lr) * F_DIM + kf * 32 + lk;
        bh[kf] = *(const f16x8*)(hi + rb);
        bl[kf] = *(const f16x8*)(lo + rb);
      }
      f32x4 acc[4] = {};
#pragma unroll
      for (int i = 0; i < 4; ++i) {
#pragma unroll
        for (int kf = 0; kf < 2; ++kf) {
          acc[i] = __builtin_amdgcn_mfma_f32_16x16x32_f16(bh[kf], ah[kf][i], acc[i], 0, 0, 0);
          acc[i] = __builtin_amdgcn_mfma_f32_16x16x32_f16(bh[kf], al[kf][i], acc[i], 0, 0, 0);
          acc[i] = __builtin_amdgcn_mfma_f32_16x16x32_f16(bl[kf], ah[kf][i], acc[i], 0, 0, 0);
        }
      }
#pragma unroll
      for (int i = 0; i < 4; ++i) {
        f32x4 v = acc[i];
        const int row = row0 + i * 16 + r_in;
        const int col = col0 + j * 16 + cb;
        const bool near = fabsf(v[0] - EMPF) < WINDOW || fabsf(v[1] - EMPF) < WINDOW ||
                          fabsf(v[2] - EMPF) < WINDOW || fabsf(v[3] - EMPF) < WINDOW;
        if (__builtin_expect(__any((int)near) && pass == 1, 0)) {
#pragma unroll
          for (int r = 0; r < 4; ++r) {
            if (fabsf(v[r] - EMPF) < WINDOW) {
              const unsigned pos = atomicAdd(&lds_cnt, 1u);
              if (pos < REG_CAP)
                region[pos] = ((unsigned)b << 24) | ((unsigned)row << 12) | (unsigned)(col + r);
            }
          }
        }
#pragma unroll
        for (int r = 0; r < 4; ++r) v[r] = (v[r] > EMPF) ? v[r] : ZEROV;
        const size_t oi = ((size_t)b << 24) + ((size_t)row << 12) + (size_t)col;
        *(f32x4*)(out + oi) = v;
      }
    }

    __syncthreads();
    if (threadIdx.x == 0 && pass == 1)
      cnt[bid] = lds_cnt < REG_CAP ? lds_cnt : REG_CAP;
  }
}

// ---------------- Kernel 3: fp64 exact recompute of near-threshold elems ----
__global__ __launch_bounds__(256) void refine_kernel(
    const float* __restrict__ x, const float* __restrict__ w,
    float* __restrict__ out, const unsigned* __restrict__ cnt,
    const unsigned* __restrict__ regions) {
  const int lane = threadIdx.x & 63;
  const unsigned wg0 = blockIdx.x * (blockDim.x >> 6) + (threadIdx.x >> 6);
  const unsigned nw = gridDim.x * (blockDim.x >> 6);
  for (unsigned rgn = wg0; rgn < N_BLOCKS; rgn += nw) {
    const unsigned count = cnt[rgn];
    const unsigned* __restrict__ region = regions + (size_t)rgn * REG_CAP;
    for (unsigned e = 0; e < count; ++e) {
      const unsigned ent = region[e];
      const int b = (int)(ent >> 24);
      const int i = (int)((ent >> 12) & 4095);
      const int j = (int)(ent & 4095);
      const double wi = (double)w[i * F_DIM + lane];
      const double wj = (double)w[j * F_DIM + lane];
      const double xi = (double)x[(b * N_ROWS + i) * F_DIM + lane];
      const double xj = (double)x[(b * N_ROWS + j) * F_DIM + lane];
      const double pi = xi * wi;
      const double pj = xj * wj;
      double si = pi * pi, sj = pj * pj, sij = pi * pj;
#pragma unroll
      for (int off = 32; off >= 1; off >>= 1) {
        si += __shfl_xor(si, off, 64);
        sj += __shfl_xor(sj, off, 64);
        sij += __shfl_xor(sij, off, 64);
      }
      if (lane == 0) {
        const double ni = fmax(sqrt(si), 1e-8);
        const double nj = fmax(sqrt(sj), 1e-8);
        const double c = sij / (ni * nj);
        const double res = (c > EMPD) ? c : (double)ZEROV;
        out[((size_t)b << 24) + ((size_t)i << 12) + (size_t)j] = (float)res;
      }
    }
  }
}

extern "C" void kernel_launch(void* const* d_in, const int* in_sizes, int n_in,
                              void* d_out, int out_size, void* d_ws, size_t ws_size,
                              hipStream_t stream) {
  const float* x = (const float*)d_in[0];
  const float* w = (const float*)d_in[1];
  float* out = (float*)d_out;

  char* ws = (char*)d_ws;
  _Float16* hi = (_Float16*)ws;                                    // 2 MB
  _Float16* lo = (_Float16*)(ws + (size_t)16384 * 64 * 2);         // 2 MB
  unsigned* cnt = (unsigned*)(ws + (size_t)4 * 1024 * 1024);       // 16 KB
  unsigned* regions = (unsigned*)(ws + (size_t)4 * 1024 * 1024 + 16384); // 4 MB

  normalize_split_kernel<<<4096, 256, 0, stream>>>(x, w, hi, lo);
  gram_kernel<<<dim3(32, 32, 4), 256, 0, stream>>>(hi, lo, out, cnt, regions);
  refine_kernel<<<1024, 256, 0, stream>>>(x, w, out, cnt, regions);
}